// Round 11
// baseline (77.749 us; speedup 1.0000x reference)
//
#include <hip/hip_runtime.h>
#include <math.h>

// ROI adaptive max-pool to 7x7 (torch adaptive_max_pool2d bin semantics).
// feature_map: [B=2, C=256, H=50, W=50] fp32
// rois:        [R=192, 5] int32 (batch, x1, y1, x2, y2), 1<=w,h, x2<=W, y2<=H
// out:         [R, C, 7, 7] fp32
//
// Round 15 = R12 structure + 8 channels/wave (was 4). The fitted model
// (t = 49.6us overhead + ~16us + 14cy*wave_loads/CU, validated on R9/R10)
// says the remaining movable terms are load count and wave count:
//  - lane = (csub: 3b, l2: 3b) -> 8 channels x 8 float2 lanes = 16 cols
//    per pass; npass = ceil((off+w)/16). Net wave-loads ~0.63x of R10,
//    waves/ROI 64 -> 32 (total per-wave VALU halves).
//  - CPB=32, grid = 192*8 = 1536; cg = XCD index under round-robin ->
//    640KB fm slice per XCD L2 (unchanged partitioning).
//  - LDS tw[32][7][54] = 48.4KB -> 3 blocks/CU (12 waves/CU; R11 showed
//    occupancy-insensitivity at 20 vs 24).
// Unchanged: k-outer/bin-inner clamped loads (dups max-neutral, L1-hot),
// 2-deep ping-pong groups, wave-local epilogue w/o __syncthreads (R12:
// neutral, fewer coupling points), predicated slot<52 stores, no d_ws
// (re-poison tax), coalesced output stores.

#define OUT_N 7
#define WPB 4                 // waves per block
#define CHW 8                 // channels per wave
#define CPB (WPB * CHW)       // 32 channels per block
#define LDSW 54               // 52 used slots (off+w<=51) + pad

__global__ __launch_bounds__(256, 4) void roicrop_kernel(
    const float* __restrict__ fm,
    const int* __restrict__ rois,
    float* __restrict__ out,
    int R, int C, int H, int W, int nfm)
{
    __shared__ float tw[CPB][OUT_N][LDSW];   // 48.4 KB

    const int lane = threadIdx.x & 63;
    const int wave = threadIdx.x >> 6;        // 0..3
    const int cg_per_r = C / CPB;             // 8
    const int r  = blockIdx.x / cg_per_r;
    const int cg = blockIdx.x - r * cg_per_r; // == XCD under round-robin

    const int csub = lane >> 3;               // channel within wave: 0..7
    const int l2   = lane & 7;                // float2 lane within channel
    const int c    = cg * CPB + wave * CHW + csub;
    const int wc   = wave * CHW + csub;       // channel-in-block

    const int* roi = rois + r * 5;
    const int b  = roi[0];
    const int x1 = roi[1];
    const int y1 = roi[2];
    const int x2 = roi[3];
    const int y2 = roi[4];
    const int h = y2 - y1;
    const int w = x2 - x1;

    // Lane covers absolute columns x0+16p+{2*l2, 2*l2+1}; x0,W even => used
    // lanes (slot < off+w) stay in-row; unused lanes may run past the row /
    // plane (values never read). Only hazard: absolute buffer end -> clamp.
    const int x0  = x1 & ~1;
    const int off = x1 - x0;                  // 0 or 1
    const unsigned base = (unsigned)(b * C + c) * (unsigned)(H * W)
                        + (unsigned)(x0 + 2 * l2);
    const unsigned lim  = (unsigned)(nfm - 2);

    // Row-bin bounds (wave-uniform). KB2 = max bin height rounded up to
    // even (extra group = clamped dups, max-neutral, L1-hot).
    int ys[OUT_N], ym[OUT_N];
    int KB = 1;
    #pragma unroll
    for (int i = 0; i < OUT_N; ++i) {
        ys[i] = y1 + (i * h) / OUT_N;
        const int ye = y1 + ((i + 1) * h + OUT_N - 1) / OUT_N;  // >= ys+1
        ym[i] = ye - 1;
        const int hb = ye - ys[i];
        KB = hb > KB ? hb : KB;
    }
    const int KB2 = (KB + 1) & ~1;

    const int npass = (off + w + 15) >> 4;    // 16-col passes: 1..4

    for (int p = 0; p < npass; ++p) {
        const unsigned pb = base + (unsigned)(16 * p);

        // Load group g (7 independent clamped loads, one per row-bin).
        #define LOADG(dst, g)                                              \
            {                                                              \
                _Pragma("unroll")                                          \
                for (int i = 0; i < OUT_N; ++i) {                          \
                    int row = ys[i] + (g);                                 \
                    if (row > ym[i]) row = ym[i];                          \
                    unsigned ia = pb + (unsigned)(row * W);                \
                    if (ia > lim) ia = lim;                                \
                    (dst)[i] = *reinterpret_cast<const float2*>(fm + ia);  \
                }                                                          \
            }
        #define REDUCE(src)                                                \
            {                                                              \
                _Pragma("unroll")                                          \
                for (int i = 0; i < OUT_N; ++i) {                          \
                    m[i].x = fmaxf(m[i].x, (src)[i].x);                    \
                    m[i].y = fmaxf(m[i].y, (src)[i].y);                    \
                }                                                          \
            }

        float2 m[OUT_N];
        #pragma unroll
        for (int i = 0; i < OUT_N; ++i) m[i] = make_float2(-INFINITY, -INFINITY);

        float2 vA[OUT_N], vB[OUT_N];
        LOADG(vA, 0)                          // 14 loads in flight before
        LOADG(vB, 1)                          // the first wait
        for (int k = 0; k < KB2; k += 2) {
            const bool more = (k + 2 < KB2);  // wave-uniform branch
            REDUCE(vA);
            if (more) LOADG(vA, k + 2)        // issue while vB in flight
            REDUCE(vB);
            if (more) LOADG(vB, k + 3)
        }
        #undef LOADG
        #undef REDUCE

        #pragma unroll
        for (int i = 0; i < OUT_N; ++i) {
            const int slot = 16 * p + 2 * l2;
            if (slot < 52) {                  // needed slots are 0..50
                *reinterpret_cast<float2*>(&tw[wc][i][slot]) = m[i];
            }
        }
    }

    // NO __syncthreads: epilogue is wave-local. This wave wrote tw[wave*CHW
    // .. wave*CHW+7]; it alone reduces/stores those 8 channels (392 outputs,
    // 64 lanes -> ~6 rounds). Intra-wave LDS RAW ordered by lgkmcnt.
    float* obase = out + ((size_t)r * C + cg * CPB + wave * CHW)
                       * (OUT_N * OUT_N);
    for (int o = lane; o < CHW * OUT_N * OUT_N; o += 64) {
        const int cc = o / (OUT_N * OUT_N);   // 0..7
        const int l  = o - cc * (OUT_N * OUT_N);
        const int i  = l / OUT_N;
        const int j  = l - i * OUT_N;
        const int xs = (j * w) / OUT_N;
        const int xe = ((j + 1) * w + OUT_N - 1) / OUT_N;
        float m2 = -INFINITY;
        for (int dx = xs; dx < xe; ++dx) {
            m2 = fmaxf(m2, tw[wave * CHW + cc][i][off + dx]);
        }
        obase[o] = m2;                        // coalesced: offset == o
    }
}

extern "C" void kernel_launch(void* const* d_in, const int* in_sizes, int n_in,
                              void* d_out, int out_size, void* d_ws, size_t ws_size,
                              hipStream_t stream)
{
    const float* fm = (const float*)d_in[0];
    const int* rois = (const int*)d_in[1];
    float* out      = (float*)d_out;

    const int R = in_sizes[1] / 5;                        // 192
    const int C = out_size / (R * OUT_N * OUT_N);         // 256
    const int H = 50;
    const int W = 50;
    const int nfm = in_sizes[0];                          // B*C*H*W elements

    const int grid = R * (C / CPB);                       // 1536
    roicrop_kernel<<<grid, 256, 0, stream>>>(fm, rois, out, R, C, H, W, nfm);
}

// Round 12
// 73.438 us; speedup vs baseline: 1.0587x; 1.0587x over previous
//
#include <hip/hip_runtime.h>
#include <math.h>

// ROI adaptive max-pool to 7x7 (torch adaptive_max_pool2d bin semantics).
// feature_map: [B=2, C=256, H=50, W=50] fp32
// rois:        [R=192, 5] int32 (batch, x1, y1, x2, y2), 1<=w,h, x2<=W, y2<=H
// out:         [R, C, 7, 7] fp32
//
// Round 16: FINAL — restore of measured-best R10 (73.7us total). Session
// findings: total = 49.6us harness overhead (256MiB re-poison fill at ~81%
// HBM peak + restores; harness-owned) + ~24us kernel. The kernel term is
// insensitive to: load count beyond this structure (R10), MLP depth /
// ping-pong (R11), occupancy 20<->24 waves/CU (R11), the block barrier
// (R12), wave count halving (R15: regresses at 12 waves/CU). Only gross
// load-instruction count ever moved it (R9: 5x loads -> +28us). This
// structure minimizes that term at adequate occupancy:
//  - k-outer/bin-inner: per k, 7 independent clamped loads (one per
//    row-bin; dup rows max-neutral, L1-hot) -> 7 in flight, rows loaded
//    ~= h+7 per channel-pass.
//  - 4 channels/wave x 32 float2 cols; one pass for ~85% of ROIs, second
//    pass for wide ones (wave-uniform).
//  - CPB=16, grid 3072, cg%8 spreads fm over the 8 XCD L2s (640KB each).
//  - LDS tw[16][7][66] = 28.9KB -> 5 blocks/CU, 20 waves/CU.
//  - no d_ws (dirtying it re-adds a ~41us re-poison per iteration).
//  - epilogue: barrier + 784 outputs across 256 threads, coalesced stores.

#define OUT_N 7
#define WPB 4                 // waves per block
#define CHW 4                 // channels per wave
#define CPB (WPB * CHW)       // 16 channels per block
#define LDSW 66               // 64 col slots + 2 pad (even: float2 aligned)

__global__ __launch_bounds__(256, 5) void roicrop_kernel(
    const float* __restrict__ fm,
    const int* __restrict__ rois,
    float* __restrict__ out,
    int R, int C, int H, int W, int nfm)
{
    __shared__ float tw[CPB][OUT_N][LDSW];   // 28.9 KB

    const int lane = threadIdx.x & 63;
    const int wave = threadIdx.x >> 6;        // 0..3
    const int cg_per_r = C / CPB;             // 16
    const int r  = blockIdx.x / cg_per_r;
    const int cg = blockIdx.x - r * cg_per_r; // cg%8 spreads fm over XCD L2s

    const int csub = lane >> 4;               // channel within wave: 0..3
    const int l2   = lane & 15;               // float2 lane within channel
    const int c    = cg * CPB + wave * CHW + csub;
    const int wc   = wave * CHW + csub;       // channel-in-block

    const int* roi = rois + r * 5;
    const int b  = roi[0];
    const int x1 = roi[1];
    const int y1 = roi[2];
    const int x2 = roi[3];
    const int y2 = roi[4];
    const int h = y2 - y1;
    const int w = x2 - x1;

    // Lane covers absolute columns x0+32p+{2*l2, 2*l2+1}; x0,W even => used
    // lanes (slot < off+w) stay in-row; only hazard is the absolute buffer
    // end (last plane's trailing lanes) -> one index clamp, values unread.
    const int x0  = x1 & ~1;
    const int off = x1 - x0;                  // 0 or 1
    const unsigned base = (unsigned)(b * C + c) * (unsigned)(H * W)
                        + (unsigned)(x0 + 2 * l2);
    const unsigned lim  = (unsigned)(nfm - 2);

    // Row-bin bounds (wave-uniform). KB = max bin height: the k-loop trip
    // count. Clamped duplicate rows are max-neutral and L1-hot.
    int ys[OUT_N], ym[OUT_N];
    int KB = 1;
    #pragma unroll
    for (int i = 0; i < OUT_N; ++i) {
        ys[i] = y1 + (i * h) / OUT_N;
        const int ye = y1 + ((i + 1) * h + OUT_N - 1) / OUT_N;  // >= ys+1
        ym[i] = ye - 1;
        const int hb = ye - ys[i];
        KB = hb > KB ? hb : KB;
    }

    const int npass = (off + w > 32) ? 2 : 1; // wide ROIs: 2nd 32-col pass

    for (int p = 0; p < npass; ++p) {
        const unsigned pb = base + (unsigned)(32 * p);

        float2 m[OUT_N];
        #pragma unroll
        for (int i = 0; i < OUT_N; ++i) m[i] = make_float2(-INFINITY, -INFINITY);

        for (int k = 0; k < KB; ++k) {
            // 7 independent loads in flight (addresses independent of data).
            float2 v[OUT_N];
            #pragma unroll
            for (int i = 0; i < OUT_N; ++i) {
                int row = ys[i] + k;
                if (row > ym[i]) row = ym[i];      // dup rows: max-neutral
                unsigned ia = pb + (unsigned)(row * W);
                if (ia > lim) ia = lim;            // buffer-end safety only
                v[i] = *reinterpret_cast<const float2*>(fm + ia);
            }
            #pragma unroll
            for (int i = 0; i < OUT_N; ++i) {
                m[i].x = fmaxf(m[i].x, v[i].x);
                m[i].y = fmaxf(m[i].y, v[i].y);
            }
        }

        #pragma unroll
        for (int i = 0; i < OUT_N; ++i) {
            *reinterpret_cast<float2*>(&tw[wc][i][32 * p + 2 * l2]) = m[i];
        }
    }
    __syncthreads();

    // Epilogue: CPB*49 = 784 outputs, 256 threads -> ~3 rounds. Column bins
    // reduce from LDS (slots are x0-relative, shifted by off).
    float* obase = out + ((size_t)r * C + cg * CPB) * (OUT_N * OUT_N);
    for (int o = threadIdx.x; o < CPB * OUT_N * OUT_N; o += 256) {
        const int twc = o / (OUT_N * OUT_N);
        const int l   = o - twc * (OUT_N * OUT_N);
        const int i   = l / OUT_N;
        const int j   = l - i * OUT_N;
        const int xs  = (j * w) / OUT_N;
        const int xe  = ((j + 1) * w + OUT_N - 1) / OUT_N;
        float m2 = -INFINITY;
        for (int dx = xs; dx < xe; ++dx) {
            m2 = fmaxf(m2, tw[twc][i][off + dx]);
        }
        obase[o] = m2;                         // fully coalesced: offset == o
    }
}

extern "C" void kernel_launch(void* const* d_in, const int* in_sizes, int n_in,
                              void* d_out, int out_size, void* d_ws, size_t ws_size,
                              hipStream_t stream)
{
    const float* fm = (const float*)d_in[0];
    const int* rois = (const int*)d_in[1];
    float* out      = (float*)d_out;

    const int R = in_sizes[1] / 5;                        // 192
    const int C = out_size / (R * OUT_N * OUT_N);         // 256
    const int H = 50;
    const int W = 50;
    const int nfm = in_sizes[0];                          // B*C*H*W elements

    const int grid = R * (C / CPB);                       // 3072
    roicrop_kernel<<<grid, 256, 0, stream>>>(fm, rois, out, R, C, H, W, nfm);
}